// Round 3
// baseline (337.901 us; speedup 1.0000x reference)
//
#include <hip/hip_runtime.h>
#include <math.h>

// Problem constants (from reference)
#define IN_F   8192
#define OUT_F  28672
#define MODE_C 0.09f
#define THR_C  0.1f

// Tiling: one wave per block; grid = NCB*NK = 112*32 = 3584 = exactly 14/CU.
#define NK      32                 // K-chunks (split-K)
#define KC      (IN_F / NK)        // 256 rows per chunk
#define TPB     64                 // one wave per block
#define COLS_PB (TPB * 4)          // 256 columns per block (float4/thread)
#define NCB     (OUT_F / COLS_PB)  // 112 column chunks

// out[j] = sum_i coeff[i]*W[i,j] + bias[j],
// coeff[i] = (|x[i]-MODE| > THR) ? x[i] : MODE
// (folds decode_bias = bias + MODE*colsum(W) into the GEMV vector)
//
// Fused split-K: each block writes its partial, device-fence, bumps a
// per-column-chunk counter; the last arriving block (ticket==NK-1) sums all
// NK partials + bias and writes out. Deterministic (fixed k-order sum).

__global__ __launch_bounds__(TPB) void gemv_fused(const float* __restrict__ x,
                                                  const float* __restrict__ w,
                                                  const float* __restrict__ bias,
                                                  float* __restrict__ partial,
                                                  int* __restrict__ counters,
                                                  float* __restrict__ out) {
    const int cb = blockIdx.x % NCB;   // column chunk (fast-varying)
    const int kc = blockIdx.x / NCB;   // k chunk

    __shared__ float coeff[KC];
    const int t = threadIdx.x;
    {
        // 64 threads x float4 = 256 coeffs
        const float4 xv = *reinterpret_cast<const float4*>(x + kc * KC + t * 4);
        float4 c;
        c.x = (fabsf(xv.x - MODE_C) > THR_C) ? xv.x : MODE_C;
        c.y = (fabsf(xv.y - MODE_C) > THR_C) ? xv.y : MODE_C;
        c.z = (fabsf(xv.z - MODE_C) > THR_C) ? xv.z : MODE_C;
        c.w = (fabsf(xv.w - MODE_C) > THR_C) ? xv.w : MODE_C;
        *reinterpret_cast<float4*>(&coeff[t * 4]) = c;
    }
    __syncthreads();

    const int col = cb * COLS_PB + t * 4;
    const float* wbase = w + (size_t)kc * KC * OUT_F + col;

    float4 acc = make_float4(0.f, 0.f, 0.f, 0.f);
#pragma unroll 8
    for (int i = 0; i < KC; ++i) {
        const float  c  = coeff[i];
        const float4 wv = *reinterpret_cast<const float4*>(wbase + (size_t)i * OUT_F);
        acc.x = fmaf(c, wv.x, acc.x);
        acc.y = fmaf(c, wv.y, acc.y);
        acc.z = fmaf(c, wv.z, acc.z);
        acc.w = fmaf(c, wv.w, acc.w);
    }

    *reinterpret_cast<float4*>(partial + (size_t)kc * OUT_F + col) = acc;

    // Release: make partial visible device-wide, then bump the chunk counter.
    __threadfence();
    __shared__ int ticket;
    if (t == 0) ticket = atomicAdd(&counters[cb], 1);
    __syncthreads();

    if (ticket == NK - 1) {
        // Acquire: ensure we see all other blocks' partial writes.
        __threadfence();
        float4 r = *reinterpret_cast<const float4*>(bias + col);
#pragma unroll
        for (int k = 0; k < NK; ++k) {
            const float4 p = *reinterpret_cast<const float4*>(partial + (size_t)k * OUT_F + col);
            r.x += p.x; r.y += p.y; r.z += p.z; r.w += p.w;
        }
        *reinterpret_cast<float4*>(out + col) = r;
    }
}

// ---- Fallback path (ws too small): init out with bias, atomic-accumulate ----

__global__ __launch_bounds__(256) void init_bias(const float* __restrict__ bias,
                                                 float* __restrict__ out) {
    const int j = blockIdx.x * 256 + threadIdx.x;
    if (j < OUT_F) out[j] = bias[j];
}

__global__ __launch_bounds__(TPB) void gemv_atomic(const float* __restrict__ x,
                                                   const float* __restrict__ w,
                                                   float* __restrict__ out) {
    const int cb = blockIdx.x % NCB;
    const int kc = blockIdx.x / NCB;

    __shared__ float coeff[KC];
    const int t = threadIdx.x;
    {
        const float4 xv = *reinterpret_cast<const float4*>(x + kc * KC + t * 4);
        float4 c;
        c.x = (fabsf(xv.x - MODE_C) > THR_C) ? xv.x : MODE_C;
        c.y = (fabsf(xv.y - MODE_C) > THR_C) ? xv.y : MODE_C;
        c.z = (fabsf(xv.z - MODE_C) > THR_C) ? xv.z : MODE_C;
        c.w = (fabsf(xv.w - MODE_C) > THR_C) ? xv.w : MODE_C;
        *reinterpret_cast<float4*>(&coeff[t * 4]) = c;
    }
    __syncthreads();

    const int col = cb * COLS_PB + t * 4;
    const float* wbase = w + (size_t)kc * KC * OUT_F + col;

    float4 acc = make_float4(0.f, 0.f, 0.f, 0.f);
#pragma unroll 8
    for (int i = 0; i < KC; ++i) {
        const float  c  = coeff[i];
        const float4 wv = *reinterpret_cast<const float4*>(wbase + (size_t)i * OUT_F);
        acc.x = fmaf(c, wv.x, acc.x);
        acc.y = fmaf(c, wv.y, acc.y);
        acc.z = fmaf(c, wv.z, acc.z);
        acc.w = fmaf(c, wv.w, acc.w);
    }

    atomicAdd(&out[col + 0], acc.x);
    atomicAdd(&out[col + 1], acc.y);
    atomicAdd(&out[col + 2], acc.z);
    atomicAdd(&out[col + 3], acc.w);
}

extern "C" void kernel_launch(void* const* d_in, const int* in_sizes, int n_in,
                              void* d_out, int out_size, void* d_ws, size_t ws_size,
                              hipStream_t stream) {
    const float* x    = (const float*)d_in[0];   // [1, 8192]
    const float* w    = (const float*)d_in[1];   // [8192, 28672]
    const float* bias = (const float*)d_in[2];   // [28672]
    float* out = (float*)d_out;

    const size_t partial_bytes = (size_t)NK * OUT_F * sizeof(float);  // 3,670,016 B (16B-aligned)
    const size_t need = partial_bytes + (size_t)NCB * sizeof(int);

    if (ws_size >= need) {
        float* partial = (float*)d_ws;
        int* counters = (int*)((char*)d_ws + partial_bytes);
        hipMemsetAsync(counters, 0, (size_t)NCB * sizeof(int), stream);
        gemv_fused<<<NCB * NK, TPB, 0, stream>>>(x, w, bias, partial, counters, out);
    } else {
        init_bias<<<(OUT_F + 255) / 256, 256, 0, stream>>>(bias, out);
        gemv_atomic<<<NCB * NK, TPB, 0, stream>>>(x, w, out);
    }
}

// Round 4
// 171.425 us; speedup vs baseline: 1.9711x; 1.9711x over previous
//
#include <hip/hip_runtime.h>
#include <math.h>

// Problem constants (from reference)
#define IN_F   8192
#define OUT_F  28672
#define MODE_C 0.09f
#define THR_C  0.1f

// Tiling: one wave per block; grid = NCB*NK = 112*32 = 3584 = exactly 14/CU.
#define NK      32                 // K-chunks (split-K)
#define KC      (IN_F / NK)        // 256 rows per chunk
#define TPB     64                 // one wave per block
#define COLS_PB (TPB * 4)          // 256 columns per block (float4/thread)
#define NCB     (OUT_F / COLS_PB)  // 112 column chunks

// out[j] = sum_i coeff[i]*W[i,j] + bias[j],
// coeff[i] = (|x[i]-MODE| > THR) ? x[i] : MODE
// (folds decode_bias = bias + MODE*colsum(W) into the GEMV vector)
//
// Split-K combine via global f32 atomicAdd (memory-side, no fence needed —
// round 3 showed per-block __threadfence() costs 2x on 8-XCD gfx950).
// out is zeroed by a memset node each call; kc==0 blocks fold the bias in.

__global__ __launch_bounds__(TPB) void gemv_atomic(const float* __restrict__ x,
                                                   const float* __restrict__ w,
                                                   const float* __restrict__ bias,
                                                   float* __restrict__ out) {
    const int cb = blockIdx.x % NCB;   // column chunk (fast-varying)
    const int kc = blockIdx.x / NCB;   // k chunk

    __shared__ float coeff[KC];
    const int t = threadIdx.x;
    {
        // 64 threads x float4 = 256 coeffs
        const float4 xv = *reinterpret_cast<const float4*>(x + kc * KC + t * 4);
        float4 c;
        c.x = (fabsf(xv.x - MODE_C) > THR_C) ? xv.x : MODE_C;
        c.y = (fabsf(xv.y - MODE_C) > THR_C) ? xv.y : MODE_C;
        c.z = (fabsf(xv.z - MODE_C) > THR_C) ? xv.z : MODE_C;
        c.w = (fabsf(xv.w - MODE_C) > THR_C) ? xv.w : MODE_C;
        *reinterpret_cast<float4*>(&coeff[t * 4]) = c;
    }
    __syncthreads();

    const int col = cb * COLS_PB + t * 4;
    const float* wbase = w + (size_t)kc * KC * OUT_F + col;

    float4 acc;
    if (kc == 0) {
        acc = *reinterpret_cast<const float4*>(bias + col);  // fold bias once
    } else {
        acc = make_float4(0.f, 0.f, 0.f, 0.f);
    }

#pragma unroll 8
    for (int i = 0; i < KC; ++i) {
        const float  c  = coeff[i];
        const float4 wv = *reinterpret_cast<const float4*>(wbase + (size_t)i * OUT_F);
        acc.x = fmaf(c, wv.x, acc.x);
        acc.y = fmaf(c, wv.y, acc.y);
        acc.z = fmaf(c, wv.z, acc.z);
        acc.w = fmaf(c, wv.w, acc.w);
    }

    // Fire-and-forget device-scope atomics (out pre-zeroed by memset node).
    atomicAdd(&out[col + 0], acc.x);
    atomicAdd(&out[col + 1], acc.y);
    atomicAdd(&out[col + 2], acc.z);
    atomicAdd(&out[col + 3], acc.w);
}

extern "C" void kernel_launch(void* const* d_in, const int* in_sizes, int n_in,
                              void* d_out, int out_size, void* d_ws, size_t ws_size,
                              hipStream_t stream) {
    const float* x    = (const float*)d_in[0];   // [1, 8192]
    const float* w    = (const float*)d_in[1];   // [8192, 28672]
    const float* bias = (const float*)d_in[2];   // [28672]
    float* out = (float*)d_out;

    (void)d_ws; (void)ws_size;

    // Zero the output each call (atomics accumulate; harness doesn't re-poison).
    hipMemsetAsync(out, 0, (size_t)OUT_F * sizeof(float), stream);
    gemv_atomic<<<NCB * NK, TPB, 0, stream>>>(x, w, bias, out);
}

// Round 6
// 149.717 us; speedup vs baseline: 2.2569x; 1.1450x over previous
//
#include <hip/hip_runtime.h>
#include <math.h>

// Problem constants (from reference)
#define IN_F   8192
#define OUT_F  28672
#define MODE_C 0.09f
#define THR_C  0.1f

// Tiling: one wave per block; grid = NCB*NK = 112*32 = 3584 = exactly 14/CU.
#define NK      32                 // K-chunks (split-K) -> partial buffer 3.67 MB
#define KC      (IN_F / NK)        // 256 rows per chunk
#define TPB     64                 // one wave per block
#define COLS_PB (TPB * 4)          // 256 columns per block (float4/thread)
#define NCB     (OUT_F / COLS_PB)  // 112 column chunks

// Native vector type for nontemporal builtins (HIP_vector_type is rejected).
typedef float f32x4 __attribute__((ext_vector_type(4)));

// out[j] = sum_i coeff[i]*W[i,j] + bias[j],
// coeff[i] = (|x[i]-MODE| > THR) ? x[i] : MODE
// (folds decode_bias = bias + MODE*colsum(W) into the GEMV vector)
//
// Structure notes from earlier rounds:
//  - per-block __threadfence() single-kernel fusion: 2x REGRESSION (round 3)
//  - atomicAdd combine: +5us vs two-kernel (round 4)
//  - two-kernel split-K (this): best. 14 blocks/CU exactly balanced.

__global__ __launch_bounds__(TPB) void gemv_partial(const float* __restrict__ x,
                                                    const float* __restrict__ w,
                                                    float* __restrict__ partial) {
    const int cb = blockIdx.x % NCB;   // column chunk (fast-varying)
    const int kc = blockIdx.x / NCB;   // k chunk

    __shared__ float coeff[KC];
    const int t = threadIdx.x;
    {
        // 64 threads x float4 = 256 coeffs
        const float4 xv = *reinterpret_cast<const float4*>(x + kc * KC + t * 4);
        float4 c;
        c.x = (fabsf(xv.x - MODE_C) > THR_C) ? xv.x : MODE_C;
        c.y = (fabsf(xv.y - MODE_C) > THR_C) ? xv.y : MODE_C;
        c.z = (fabsf(xv.z - MODE_C) > THR_C) ? xv.z : MODE_C;
        c.w = (fabsf(xv.w - MODE_C) > THR_C) ? xv.w : MODE_C;
        *reinterpret_cast<float4*>(&coeff[t * 4]) = c;
    }
    __syncthreads();

    const int col = cb * COLS_PB + t * 4;
    const float* wbase = w + (size_t)kc * KC * OUT_F + col;

    float4 acc = make_float4(0.f, 0.f, 0.f, 0.f);
    // 16 outstanding non-temporal 16B loads per thread (streaming, zero reuse)
#pragma unroll 16
    for (int i = 0; i < KC; ++i) {
        const float c = coeff[i];
        const f32x4 wv = __builtin_nontemporal_load(
            reinterpret_cast<const f32x4*>(wbase + (size_t)i * OUT_F));
        acc.x = fmaf(c, wv.x, acc.x);
        acc.y = fmaf(c, wv.y, acc.y);
        acc.z = fmaf(c, wv.z, acc.z);
        acc.w = fmaf(c, wv.w, acc.w);
    }

    *reinterpret_cast<float4*>(partial + (size_t)kc * OUT_F + col) = acc;
}

// 112 blocks x 64 threads: one float4 column-group per thread, 32 independent
// partial loads in flight (IC-resident), deterministic fixed-order sum.
__global__ __launch_bounds__(TPB) void reduce_bias(const float* __restrict__ partial,
                                                   const float* __restrict__ bias,
                                                   float* __restrict__ out) {
    const int j = (blockIdx.x * TPB + threadIdx.x) * 4;
    float4 acc = *reinterpret_cast<const float4*>(bias + j);
#pragma unroll
    for (int k = 0; k < NK; ++k) {
        const float4 p = *reinterpret_cast<const float4*>(partial + (size_t)k * OUT_F + j);
        acc.x += p.x; acc.y += p.y; acc.z += p.z; acc.w += p.w;
    }
    *reinterpret_cast<float4*>(out + j) = acc;
}

// ---- Fallback path (ws too small): init out with bias, atomic-accumulate ----

__global__ __launch_bounds__(256) void init_bias(const float* __restrict__ bias,
                                                 float* __restrict__ out) {
    const int j = blockIdx.x * 256 + threadIdx.x;
    if (j < OUT_F) out[j] = bias[j];
}

__global__ __launch_bounds__(TPB) void gemv_atomic(const float* __restrict__ x,
                                                   const float* __restrict__ w,
                                                   float* __restrict__ out) {
    const int cb = blockIdx.x % NCB;
    const int kc = blockIdx.x / NCB;

    __shared__ float coeff[KC];
    const int t = threadIdx.x;
    {
        const float4 xv = *reinterpret_cast<const float4*>(x + kc * KC + t * 4);
        float4 c;
        c.x = (fabsf(xv.x - MODE_C) > THR_C) ? xv.x : MODE_C;
        c.y = (fabsf(xv.y - MODE_C) > THR_C) ? xv.y : MODE_C;
        c.z = (fabsf(xv.z - MODE_C) > THR_C) ? xv.z : MODE_C;
        c.w = (fabsf(xv.w - MODE_C) > THR_C) ? xv.w : MODE_C;
        *reinterpret_cast<float4*>(&coeff[t * 4]) = c;
    }
    __syncthreads();

    const int col = cb * COLS_PB + t * 4;
    const float* wbase = w + (size_t)kc * KC * OUT_F + col;

    float4 acc = make_float4(0.f, 0.f, 0.f, 0.f);
#pragma unroll 16
    for (int i = 0; i < KC; ++i) {
        const float  c  = coeff[i];
        const float4 wv = *reinterpret_cast<const float4*>(wbase + (size_t)i * OUT_F);
        acc.x = fmaf(c, wv.x, acc.x);
        acc.y = fmaf(c, wv.y, acc.y);
        acc.z = fmaf(c, wv.z, acc.z);
        acc.w = fmaf(c, wv.w, acc.w);
    }

    atomicAdd(&out[col + 0], acc.x);
    atomicAdd(&out[col + 1], acc.y);
    atomicAdd(&out[col + 2], acc.z);
    atomicAdd(&out[col + 3], acc.w);
}

extern "C" void kernel_launch(void* const* d_in, const int* in_sizes, int n_in,
                              void* d_out, int out_size, void* d_ws, size_t ws_size,
                              hipStream_t stream) {
    const float* x    = (const float*)d_in[0];   // [1, 8192]
    const float* w    = (const float*)d_in[1];   // [8192, 28672]
    const float* bias = (const float*)d_in[2];   // [28672]
    float* out = (float*)d_out;

    const size_t need = (size_t)NK * OUT_F * sizeof(float);  // ~3.67 MB

    if (ws_size >= need) {
        float* partial = (float*)d_ws;
        gemv_partial<<<NCB * NK, TPB, 0, stream>>>(x, w, partial);
        reduce_bias<<<OUT_F / (TPB * 4), TPB, 0, stream>>>(partial, bias, out);
    } else {
        init_bias<<<(OUT_F + 255) / 256, 256, 0, stream>>>(bias, out);
        gemv_atomic<<<NCB * NK, TPB, 0, stream>>>(x, w, out);
    }
}